// Round 4
// baseline (3014.232 us; speedup 1.0000x reference)
//
#include <hip/hip_runtime.h>
#include <hip/hip_bf16.h>

#define NB 2
#define NN 4096
#define ND 1024
#define NE 128
#define NHID 64
#define NK 16

// ---------------- prep: A = W1a+W1c, Bm = W1b-W1c ----------------
__global__ void k_prep(const float* __restrict__ W1, float* __restrict__ A, float* __restrict__ Bm) {
    int i = blockIdx.x * 256 + threadIdx.x;   // 0..8191 = c*64+e
    A[i]  = W1[i]           + W1[256 * 64 + i];
    Bm[i] = W1[128 * 64 + i] - W1[256 * 64 + i];
}

// ---------------- pool (and optional transpose) ----------------
// X: (B, 1024, 4096).  pool: (B, 256, 4096).  hft: (B, 4096, 1024)
template<bool DO_T>
__global__ void k_pool_t(const float* __restrict__ X, float* __restrict__ pool, float* __restrict__ hft) {
    int nt = blockIdx.x;          // 0..63 n-tile
    int c  = blockIdx.y;          // 0..15 channel
    int b  = blockIdx.z;
    int t  = threadIdx.x;
    int nn_base = t & 63;
    int g = t >> 6;               // 0..3
    int n0 = nt * 64;
    const float* Xb = X + ((size_t)b * ND + c * 64) * NN + n0;
    __shared__ __align__(16) float xs[64 * 65];

#pragma unroll
    for (int pp = 0; pp < 4; ++pp) {
        int pi16 = pp * 4 + g;
        float s = 0.f;
#pragma unroll
        for (int j = 0; j < 4; ++j) {
            int p = ((pi16 >> 2) << 1) + (j >> 1);
            int q = ((pi16 & 3) << 1) + (j & 1);
            int dl = p * 8 + q;
            float v = Xb[(size_t)dl * NN + nn_base];
            if (DO_T) xs[dl * 65 + nn_base] = v;
            s += v;
        }
        pool[((size_t)b * 256 + c * 16 + pi16) * NN + n0 + nn_base] = s * 0.25f;
    }
    if (DO_T) {
        __syncthreads();
        int dd = t & 63;
#pragma unroll
        for (int i = 0; i < 16; ++i) {
            int nn = i * 4 + g;
            hft[((size_t)b * NN + n0 + nn) * ND + c * 64 + dd] = xs[dd * 65 + nn];
        }
    }
}

// ---------------- encode GEMM: pooled^T (64n x 256) @ W (256x128) + b ----------------
__global__ void k_encode(const float* __restrict__ pool, const float* __restrict__ W,
                         const float* __restrict__ bias, float* __restrict__ emb) {
    int nt = blockIdx.x; int b = blockIdx.y;
    int t = threadIdx.x;
    int n0 = nt * 64;
    int nl = (t & 15) * 4, e0 = (t >> 4) * 8;
    __shared__ __align__(16) float xs[32 * 64];
    __shared__ __align__(16) float wc[32 * 128];
    float acc[4][8] = {};

    for (int d0 = 0; d0 < 256; d0 += 32) {
        __syncthreads();
#pragma unroll
        for (int i = 0; i < 8; ++i) {
            int l = i * 256 + t; int dd = l >> 6, nn = l & 63;
            xs[l] = pool[((size_t)b * 256 + d0 + dd) * NN + n0 + nn];
        }
#pragma unroll
        for (int i = 0; i < 16; ++i) {
            int l = i * 256 + t; int dd = l >> 7, e = l & 127;
            wc[l] = W[(d0 + dd) * NE + e];
        }
        __syncthreads();
#pragma unroll
        for (int dd = 0; dd < 32; ++dd) {
            float4 x = *(float4*)&xs[dd * 64 + nl];
            float w[8];
            *(float4*)&w[0] = *(float4*)&wc[dd * NE + e0];
            *(float4*)&w[4] = *(float4*)&wc[dd * NE + e0 + 4];
            float xv[4] = {x.x, x.y, x.z, x.w};
#pragma unroll
            for (int i = 0; i < 4; ++i)
#pragma unroll
                for (int j = 0; j < 8; ++j) acc[i][j] += xv[i] * w[j];
        }
    }
#pragma unroll
    for (int i = 0; i < 4; ++i) {
        float o[8];
#pragma unroll
        for (int j = 0; j < 8; ++j) o[j] = acc[i][j] + bias[e0 + j];
        *(float4*)&emb[((size_t)b * NN + n0 + nl + i) * NE + e0]     = *(float4*)&o[0];
        *(float4*)&emb[((size_t)b * NN + n0 + nl + i) * NE + e0 + 4] = *(float4*)&o[4];
    }
}

// ---------------- small GEMM: X (8192x128) @ Wm (128x64) [+bias] ----------------
__global__ void k_small(const float* __restrict__ Xrm, const float* __restrict__ Wm,
                        const float* __restrict__ bias, float* __restrict__ out) {
    int m0 = blockIdx.x * 64;
    int t = threadIdx.x;
    int nl = (t & 15) * 4, e0 = (t >> 4) * 4;
    __shared__ __align__(16) float xs[128 * 68];
    __shared__ __align__(16) float wc[128 * 64];
#pragma unroll
    for (int i = 0; i < 32; ++i) {
        int l = i * 256 + t; int nn = l >> 7, kk = l & 127;
        xs[kk * 68 + nn] = Xrm[(size_t)(m0 + nn) * NE + kk];
    }
#pragma unroll
    for (int i = 0; i < 32; ++i) {
        int l = i * 256 + t;
        wc[l] = Wm[l];
    }
    __syncthreads();
    float acc[4][4] = {};
#pragma unroll
    for (int kk = 0; kk < 128; ++kk) {
        float4 x = *(float4*)&xs[kk * 68 + nl];
        float4 w = *(float4*)&wc[kk * 64 + e0];
        float xv[4] = {x.x, x.y, x.z, x.w};
        float wv[4] = {w.x, w.y, w.z, w.w};
#pragma unroll
        for (int i = 0; i < 4; ++i)
#pragma unroll
            for (int j = 0; j < 4; ++j) acc[i][j] += xv[i] * wv[j];
    }
    float bv[4] = {0.f, 0.f, 0.f, 0.f};
    if (bias) { bv[0] = bias[e0]; bv[1] = bias[e0 + 1]; bv[2] = bias[e0 + 2]; bv[3] = bias[e0 + 3]; }
#pragma unroll
    for (int i = 0; i < 4; ++i) {
        float4 o = {acc[i][0] + bv[0], acc[i][1] + bv[1], acc[i][2] + bv[2], acc[i][3] + bv[3]};
        *(float4*)&out[(size_t)(m0 + nl + i) * 64 + e0] = o;
    }
}

// ---------------- top-k (k=16) per row of 4096 ----------------
// Tie-break: JAX top_k prefers the LOWER index on equal values. Pack the
// low 32 bits as (NN-1-idx) so the packed-u64 max picks the lower index.
__device__ __forceinline__ unsigned enc_f(unsigned u) {
    return u ^ ((unsigned)((int)u >> 31) | 0x80000000u);
}
__device__ __forceinline__ float dec_f(unsigned m) {
    unsigned u = (m & 0x80000000u) ? (m ^ 0x80000000u) : ~m;
    return __uint_as_float(u);
}

__global__ void k_topk(const float* __restrict__ attn, float* __restrict__ prior, int* __restrict__ idxo) {
    int row = blockIdx.x;   // b*4096+n
    const float* a = attn + (size_t)row * NN;
    int t = threadIdx.x;
    int lane = t & 63, wv = t >> 6;
    unsigned long long pk[16];
#pragma unroll
    for (int i = 0; i < 16; ++i) {
        int pos = i * 256 + t;
        unsigned ub = enc_f(__float_as_uint(a[pos]));
        pk[i] = ((unsigned long long)ub << 32) | (unsigned)(NN - 1 - pos);
    }
    __shared__ unsigned long long red[4];
    __shared__ unsigned long long win;
    for (int r = 0; r < NK; ++r) {
        unsigned long long m = pk[0];
#pragma unroll
        for (int i = 1; i < 16; ++i) m = (pk[i] > m) ? pk[i] : m;
#pragma unroll
        for (int off = 32; off > 0; off >>= 1) {
            unsigned long long o = __shfl_xor(m, off, 64);
            m = (o > m) ? o : m;
        }
        if (lane == 0) red[wv] = m;
        __syncthreads();
        if (t == 0) {
            unsigned long long w01 = (red[0] > red[1]) ? red[0] : red[1];
            unsigned long long w23 = (red[2] > red[3]) ? red[2] : red[3];
            unsigned long long w0 = (w01 > w23) ? w01 : w23;
            win = w0;
            prior[(size_t)row * NK + r] = dec_f((unsigned)(w0 >> 32));
            idxo[(size_t)row * NK + r] = NN - 1 - (int)(w0 & 0xFFFFFFFFull);
        }
        __syncthreads();
        unsigned long long w0 = win;
#pragma unroll
        for (int i = 0; i < 16; ++i) if (pk[i] == w0) pk[i] = 0ull;
    }
}

// ---------------- rescore + softmax + gather ----------------
__global__ void k_rescore(const float* __restrict__ prior, const int* __restrict__ idxs,
                          const float* __restrict__ q_emb, const float* __restrict__ key_emb,
                          const float* __restrict__ qA, const float* __restrict__ kB,
                          const float* __restrict__ W1, const float* __restrict__ W2,
                          const float* __restrict__ b2,
                          const float* __restrict__ hft, float* __restrict__ out) {
    int row = blockIdx.x;       // b*4096+n
    int b = row >> 12;
    int t = threadIdx.x;
    int lane = t & 63, wv = t >> 6;
    __shared__ __align__(16) float w1d[128 * 64];
    __shared__ __align__(16) float qk[16 * 128];
    __shared__ __align__(16) float kbs[16 * 64];
    __shared__ float ps[16];
    __shared__ int   is_[16];
    __shared__ float lg[16];

#pragma unroll
    for (int i = 0; i < 32; ++i) w1d[i * 256 + t] = W1[384 * 64 + i * 256 + t];
    if (t < 16) { ps[t] = prior[(size_t)row * NK + t]; is_[t] = idxs[(size_t)row * NK + t]; }
    __syncthreads();

    {   // stage qk = q .* k_sel  and kbs = kB[idx]
        int k = t >> 4, i = t & 15;
        int j = is_[k];
        const float* qrow = q_emb + (size_t)row * NE;
        const float* krow = key_emb + ((size_t)b * NN + j) * NE;
        int c0 = i * 8;
#pragma unroll
        for (int c = 0; c < 8; ++c) qk[k * NE + c0 + c] = qrow[c0 + c] * krow[c0 + c];
        const float* kbrow = kB + ((size_t)b * NN + j) * 64;
        int e4 = i * 4;
        *(float4*)&kbs[k * 64 + e4] = *(const float4*)&kbrow[e4];
    }
    __syncthreads();

    float acc[4] = {0.f, 0.f, 0.f, 0.f};
    for (int c4 = 0; c4 < 32; ++c4) {
        float w0 = w1d[(c4 * 4 + 0) * 64 + lane];
        float w1 = w1d[(c4 * 4 + 1) * 64 + lane];
        float w2 = w1d[(c4 * 4 + 2) * 64 + lane];
        float w3 = w1d[(c4 * 4 + 3) * 64 + lane];
#pragma unroll
        for (int kk = 0; kk < 4; ++kk) {
            float4 q4 = *(float4*)&qk[(wv * 4 + kk) * NE + c4 * 4];
            acc[kk] += q4.x * w0 + q4.y * w1 + q4.z * w2 + q4.w * w3;
        }
    }
    float qa  = qA[(size_t)row * 64 + lane];
    float wl  = W1[512 * 64 + lane];
    float w2e = W2[lane];
#pragma unroll
    for (int kk = 0; kk < 4; ++kk) {
        int k = wv * 4 + kk;
        float h = acc[kk] + qa + kbs[k * 64 + lane] + ps[k] * wl;
        float th = tanhf(0.7978845608028654f * (h + 0.044715f * h * h * h));
        float g = 0.5f * h * (1.f + th);
        float r = g * w2e;
#pragma unroll
        for (int off = 32; off > 0; off >>= 1) r += __shfl_xor(r, off, 64);
        if (lane == 0) lg[k] = logf(fmaxf(ps[k], 1e-8f)) + r + b2[0];
    }
    __syncthreads();

    float wk[16];
    float mx = -1e30f;
#pragma unroll
    for (int k = 0; k < 16; ++k) mx = fmaxf(mx, lg[k]);
    float sum = 0.f;
#pragma unroll
    for (int k = 0; k < 16; ++k) { wk[k] = expf(lg[k] - mx); sum += wk[k]; }
    float inv = 1.f / sum;

    int d0 = t * 4;
    float4 o = {0.f, 0.f, 0.f, 0.f};
#pragma unroll
    for (int k = 0; k < 16; ++k) {
        const float4 v = *(const float4*)&hft[((size_t)b * NN + is_[k]) * ND + d0];
        float w = wk[k] * inv;
        o.x += w * v.x; o.y += w * v.y; o.z += w * v.z; o.w += w * v.w;
    }
    *(float4*)&out[(size_t)row * ND + d0] = o;
}

// ---------------- launcher ----------------
extern "C" void kernel_launch(void* const* d_in, const int* in_sizes, int n_in,
                              void* d_out, int out_size, void* d_ws, size_t ws_size,
                              hipStream_t stream) {
    const float* hr_attn = (const float*)d_in[0];
    const float* hr_hf   = (const float*)d_in[1];
    const float* base_hf = (const float*)d_in[2];
    const float* Wq = (const float*)d_in[3];
    const float* bq = (const float*)d_in[4];
    const float* Wk = (const float*)d_in[5];
    const float* bk = (const float*)d_in[6];
    const float* W1 = (const float*)d_in[7];
    const float* b1 = (const float*)d_in[8];
    const float* W2 = (const float*)d_in[9];
    const float* b2 = (const float*)d_in[10];
    float* out = (float*)d_out;

    float* ws = (float*)d_ws;
    float* hft   = ws;                          // 2*4096*1024 = 8388608
    float* poolK = hft + 8388608;               // 2*256*4096  = 2097152
    float* poolQ = poolK + 2097152;
    float* kemb  = poolQ + 2097152;             // 2*4096*128  = 1048576
    float* qemb  = kemb + 1048576;
    float* kBw   = qemb + 1048576;              // 2*4096*64   = 524288
    float* qAw   = kBw + 524288;
    float* Amat  = qAw + 524288;                // 8192
    float* Bmat  = Amat + 8192;                 // 8192
    float* priw  = Bmat + 8192;                 // 2*4096*16   = 131072
    int*   idxw  = (int*)(priw + 131072);       // 131072

    k_prep<<<32, 256, 0, stream>>>(W1, Amat, Bmat);
    k_pool_t<true><<<dim3(64, 16, NB), 256, 0, stream>>>(hr_hf, poolK, hft);
    k_pool_t<false><<<dim3(64, 16, NB), 256, 0, stream>>>(base_hf, poolQ, nullptr);
    k_encode<<<dim3(64, NB), 256, 0, stream>>>(poolK, Wk, bk, kemb);
    k_encode<<<dim3(64, NB), 256, 0, stream>>>(poolQ, Wq, bq, qemb);
    k_small<<<128, 256, 0, stream>>>(kemb, Bmat, nullptr, kBw);
    k_small<<<128, 256, 0, stream>>>(qemb, Amat, b1, qAw);
    k_topk<<<NB * NN, 256, 0, stream>>>(hr_attn, priw, idxw);
    k_rescore<<<NB * NN, 256, 0, stream>>>(priw, idxw, qemb, kemb, qAw, kBw,
                                           W1, W2, b2, hft, out);
}

// Round 5
// 1246.863 us; speedup vs baseline: 2.4175x; 2.4175x over previous
//
#include <hip/hip_runtime.h>
#include <hip/hip_bf16.h>

#define NB 2
#define NN 4096
#define ND 1024
#define NE 128
#define NHID 64
#define NK 16

// ---------------- prep: A = W1a+W1c, Bm = W1b-W1c ----------------
__global__ void k_prep(const float* __restrict__ W1, float* __restrict__ A, float* __restrict__ Bm) {
    int i = blockIdx.x * 256 + threadIdx.x;   // 0..8191 = c*64+e
    A[i]  = W1[i]           + W1[256 * 64 + i];
    Bm[i] = W1[128 * 64 + i] - W1[256 * 64 + i];
}

// ---------------- pool (and optional transpose) ----------------
// X: (B, 1024, 4096).  pool: (B, 256, 4096).  hft: (B, 4096, 1024)
template<bool DO_T>
__global__ void k_pool_t(const float* __restrict__ X, float* __restrict__ pool, float* __restrict__ hft) {
    int nt = blockIdx.x;          // 0..63 n-tile
    int c  = blockIdx.y;          // 0..15 channel
    int b  = blockIdx.z;
    int t  = threadIdx.x;
    int nn_base = t & 63;
    int g = t >> 6;               // 0..3
    int n0 = nt * 64;
    const float* Xb = X + ((size_t)b * ND + c * 64) * NN + n0;
    __shared__ __align__(16) float xs[64 * 65];

#pragma unroll
    for (int pp = 0; pp < 4; ++pp) {
        int pi16 = pp * 4 + g;
        float s = 0.f;
#pragma unroll
        for (int j = 0; j < 4; ++j) {
            int p = ((pi16 >> 2) << 1) + (j >> 1);
            int q = ((pi16 & 3) << 1) + (j & 1);
            int dl = p * 8 + q;
            float v = Xb[(size_t)dl * NN + nn_base];
            if (DO_T) xs[dl * 65 + nn_base] = v;
            s += v;
        }
        pool[((size_t)b * 256 + c * 16 + pi16) * NN + n0 + nn_base] = s * 0.25f;
    }
    if (DO_T) {
        __syncthreads();
        int dd = t & 63;
#pragma unroll
        for (int i = 0; i < 16; ++i) {
            int nn = i * 4 + g;
            hft[((size_t)b * NN + n0 + nn) * ND + c * 64 + dd] = xs[dd * 65 + nn];
        }
    }
}

// ---------------- encode GEMM: pooled^T (64n x 256) @ W (256x128) + b ----------------
__global__ void k_encode(const float* __restrict__ pool, const float* __restrict__ W,
                         const float* __restrict__ bias, float* __restrict__ emb) {
    int nt = blockIdx.x; int b = blockIdx.y;
    int t = threadIdx.x;
    int n0 = nt * 64;
    int nl = (t & 15) * 4, e0 = (t >> 4) * 8;
    __shared__ __align__(16) float xs[32 * 64];
    __shared__ __align__(16) float wc[32 * 128];
    float acc[4][8] = {};

    for (int d0 = 0; d0 < 256; d0 += 32) {
        __syncthreads();
#pragma unroll
        for (int i = 0; i < 8; ++i) {
            int l = i * 256 + t; int dd = l >> 6, nn = l & 63;
            xs[l] = pool[((size_t)b * 256 + d0 + dd) * NN + n0 + nn];
        }
#pragma unroll
        for (int i = 0; i < 16; ++i) {
            int l = i * 256 + t; int dd = l >> 7, e = l & 127;
            wc[l] = W[(d0 + dd) * NE + e];
        }
        __syncthreads();
#pragma unroll
        for (int dd = 0; dd < 32; ++dd) {
            float4 x = *(float4*)&xs[dd * 64 + nl];
            float w[8];
            *(float4*)&w[0] = *(float4*)&wc[dd * NE + e0];
            *(float4*)&w[4] = *(float4*)&wc[dd * NE + e0 + 4];
            float xv[4] = {x.x, x.y, x.z, x.w};
#pragma unroll
            for (int i = 0; i < 4; ++i)
#pragma unroll
                for (int j = 0; j < 8; ++j) acc[i][j] += xv[i] * w[j];
        }
    }
#pragma unroll
    for (int i = 0; i < 4; ++i) {
        float o[8];
#pragma unroll
        for (int j = 0; j < 8; ++j) o[j] = acc[i][j] + bias[e0 + j];
        *(float4*)&emb[((size_t)b * NN + n0 + nl + i) * NE + e0]     = *(float4*)&o[0];
        *(float4*)&emb[((size_t)b * NN + n0 + nl + i) * NE + e0 + 4] = *(float4*)&o[4];
    }
}

// ---------------- small GEMM: X (8192x128) @ Wm (128x64) [+bias] ----------------
__global__ void k_small(const float* __restrict__ Xrm, const float* __restrict__ Wm,
                        const float* __restrict__ bias, float* __restrict__ out) {
    int m0 = blockIdx.x * 64;
    int t = threadIdx.x;
    int nl = (t & 15) * 4, e0 = (t >> 4) * 4;
    __shared__ __align__(16) float xs[128 * 68];
    __shared__ __align__(16) float wc[128 * 64];
#pragma unroll
    for (int i = 0; i < 32; ++i) {
        int l = i * 256 + t; int nn = l >> 7, kk = l & 127;
        xs[kk * 68 + nn] = Xrm[(size_t)(m0 + nn) * NE + kk];
    }
#pragma unroll
    for (int i = 0; i < 32; ++i) {
        int l = i * 256 + t;
        wc[l] = Wm[l];
    }
    __syncthreads();
    float acc[4][4] = {};
#pragma unroll
    for (int kk = 0; kk < 128; ++kk) {
        float4 x = *(float4*)&xs[kk * 68 + nl];
        float4 w = *(float4*)&wc[kk * 64 + e0];
        float xv[4] = {x.x, x.y, x.z, x.w};
        float wv[4] = {w.x, w.y, w.z, w.w};
#pragma unroll
        for (int i = 0; i < 4; ++i)
#pragma unroll
            for (int j = 0; j < 4; ++j) acc[i][j] += xv[i] * wv[j];
    }
    float bv[4] = {0.f, 0.f, 0.f, 0.f};
    if (bias) { bv[0] = bias[e0]; bv[1] = bias[e0 + 1]; bv[2] = bias[e0 + 2]; bv[3] = bias[e0 + 3]; }
#pragma unroll
    for (int i = 0; i < 4; ++i) {
        float4 o = {acc[i][0] + bv[0], acc[i][1] + bv[1], acc[i][2] + bv[2], acc[i][3] + bv[3]};
        *(float4*)&out[(size_t)(m0 + nl + i) * 64 + e0] = o;
    }
}

// ---------------- top-k (k=16) per row of 4096 ----------------
// Tie-break: JAX top_k prefers the LOWER index on equal values. Pack the
// low 32 bits as (NN-1-idx) so the packed-u64 max picks the lower index.
__device__ __forceinline__ unsigned enc_f(unsigned u) {
    return u ^ ((unsigned)((int)u >> 31) | 0x80000000u);
}
__device__ __forceinline__ float dec_f(unsigned m) {
    unsigned u = (m & 0x80000000u) ? (m ^ 0x80000000u) : ~m;
    return __uint_as_float(u);
}

__global__ void k_topk(const float* __restrict__ attn, float* __restrict__ prior, int* __restrict__ idxo) {
    int row = blockIdx.x;   // b*4096+n
    const float* a = attn + (size_t)row * NN;
    int t = threadIdx.x;
    int lane = t & 63, wv = t >> 6;
    unsigned long long pk[16];
#pragma unroll
    for (int i = 0; i < 16; ++i) {
        int pos = i * 256 + t;
        unsigned ub = enc_f(__float_as_uint(a[pos]));
        pk[i] = ((unsigned long long)ub << 32) | (unsigned)(NN - 1 - pos);
    }
    __shared__ unsigned long long red[4];
    __shared__ unsigned long long win;
    for (int r = 0; r < NK; ++r) {
        unsigned long long m = pk[0];
#pragma unroll
        for (int i = 1; i < 16; ++i) m = (pk[i] > m) ? pk[i] : m;
#pragma unroll
        for (int off = 32; off > 0; off >>= 1) {
            unsigned long long o = __shfl_xor(m, off, 64);
            m = (o > m) ? o : m;
        }
        if (lane == 0) red[wv] = m;
        __syncthreads();
        if (t == 0) {
            unsigned long long w01 = (red[0] > red[1]) ? red[0] : red[1];
            unsigned long long w23 = (red[2] > red[3]) ? red[2] : red[3];
            unsigned long long w0 = (w01 > w23) ? w01 : w23;
            win = w0;
            prior[(size_t)row * NK + r] = dec_f((unsigned)(w0 >> 32));
            idxo[(size_t)row * NK + r] = NN - 1 - (int)(w0 & 0xFFFFFFFFull);
        }
        __syncthreads();
        unsigned long long w0 = win;
#pragma unroll
        for (int i = 0; i < 16; ++i) if (pk[i] == w0) pk[i] = 0ull;
    }
}

// ---------------- MLP rescore + softmax -> weights (B,N,16) ----------------
// Block = 4 rows; wave wv owns row r0+wv, lane = hidden unit e.
__global__ void k_mlpw(const float* __restrict__ prior, const int* __restrict__ idxs,
                       const float* __restrict__ qemb, const float* __restrict__ kemb,
                       const float* __restrict__ qA, const float* __restrict__ kB,
                       const float* __restrict__ W1, const float* __restrict__ W2,
                       const float* __restrict__ b2, float* __restrict__ wout) {
    int bid = blockIdx.x;          // 0..2047
    int t = threadIdx.x;
    int lane = t & 63, wv = t >> 6;
    int r0 = bid * 4;
    __shared__ __align__(16) float w1d[128 * 64];   // 32 KB, block-shared
    __shared__ __align__(16) float qk[64 * 128];    // 32 KB, slot = (row&3)*16+k
    __shared__ float ps[64];
    __shared__ int   js[64];

#pragma unroll
    for (int i = 0; i < 32; ++i) w1d[i * 256 + t] = W1[384 * 64 + i * 256 + t];
    if (t < 64) {
        int r = r0 + (t >> 4);
        ps[t] = prior[(size_t)r * NK + (t & 15)];
        js[t] = idxs[(size_t)r * NK + (t & 15)];
    }
    __syncthreads();

    {   // stage qk products: 4 threads per slot, 32 c's each
        int s = t >> 2, qc = t & 3;
        int r = r0 + (s >> 4);
        int b = r >> 12;
        int j = js[s];
        const float* qrow = qemb + (size_t)r * NE + qc * 32;
        const float* krow = kemb + ((size_t)(b << 12) + j) * NE + qc * 32;
        float* dst = qk + s * NE + qc * 32;
#pragma unroll
        for (int c = 0; c < 32; c += 4) {
            float4 qv = *(const float4*)&qrow[c];
            float4 kv = *(const float4*)&krow[c];
            dst[c]     = qv.x * kv.x;
            dst[c + 1] = qv.y * kv.y;
            dst[c + 2] = qv.z * kv.z;
            dst[c + 3] = qv.w * kv.w;
        }
    }
    __syncthreads();

    int r = r0 + wv;
    int b = r >> 12;
    float qa  = qA[(size_t)r * 64 + lane];
    float wl  = W1[512 * 64 + lane];
    float w2e = W2[lane];
    float bb2 = b2[0];
    float lgk[16];
#pragma unroll
    for (int k = 0; k < 16; ++k) {
        const float* qkr = qk + (wv * 16 + k) * NE;
        float acc = 0.f;
#pragma unroll
        for (int c = 0; c < 128; ++c) acc += qkr[c] * w1d[c * 64 + lane];
        int j = js[wv * 16 + k];
        float h = acc + qa + kB[((size_t)(b << 12) + j) * 64 + lane] + ps[wv * 16 + k] * wl;
        float th = tanhf(0.7978845608028654f * (h + 0.044715f * h * h * h));
        float g = 0.5f * h * (1.f + th);
        float rs = g * w2e;
#pragma unroll
        for (int off = 32; off > 0; off >>= 1) rs += __shfl_xor(rs, off, 64);
        lgk[k] = logf(fmaxf(ps[wv * 16 + k], 1e-8f)) + rs + bb2;
    }
    // softmax over 16, redundantly per lane (cheap), lanes 0..15 write
    float mx = lgk[0];
#pragma unroll
    for (int k = 1; k < 16; ++k) mx = fmaxf(mx, lgk[k]);
    float sum = 0.f;
    float wkk[16];
#pragma unroll
    for (int k = 0; k < 16; ++k) { wkk[k] = expf(lgk[k] - mx); sum += wkk[k]; }
    float inv = 1.f / sum;
    if (lane < 16) wout[(size_t)r * NK + lane] = wkk[lane] * inv;
}

// ---------------- weighted gather, d-tiled for per-XCD L2 residency ----------------
// blockIdx: dt = id&7 (512B d-slice -> one XCD if round-robin), b, 64-row chunk.
// Sub-table hft[b][:, dt*128:(dt+1)*128] = 4096*512B = 2MB... x2 rows = 4MB fits L2.
__global__ void k_gather(const float* __restrict__ wsm, const int* __restrict__ idxs,
                         const float* __restrict__ hft, float* __restrict__ out) {
    int id = blockIdx.x;            // 0..1023
    int dt = id & 7;
    int rest = id >> 3;
    int b = rest >> 6;
    int nc = rest & 63;             // 64-row chunk
    int t = threadIdx.x;
    __shared__ float ws[64 * 16];
    __shared__ int   is[64 * 16];
#pragma unroll
    for (int i = 0; i < 4; ++i) {
        int l = i * 256 + t;        // slot = row*16+k
        size_t r = (size_t)(b << 12) + nc * 64 + (l >> 4);
        ws[l] = wsm[r * NK + (l & 15)];
        is[l] = idxs[r * NK + (l & 15)];
    }
    __syncthreads();
    int rg = t >> 5;                // 0..7
    int l32 = t & 31;
    const float* hb = hft + ((size_t)(b << 12)) * ND + dt * 128 + l32 * 4;
    for (int rr = rg; rr < 64; rr += 8) {
        float4 o = {0.f, 0.f, 0.f, 0.f};
#pragma unroll
        for (int k = 0; k < 16; ++k) {
            float w = ws[rr * 16 + k];
            const float4 v = *(const float4*)&hb[(size_t)is[rr * 16 + k] * ND];
            o.x += w * v.x; o.y += w * v.y; o.z += w * v.z; o.w += w * v.w;
        }
        int n = nc * 64 + rr;
        *(float4*)&out[((size_t)(b << 12) + n) * ND + dt * 128 + l32 * 4] = o;
    }
}

// ---------------- launcher ----------------
extern "C" void kernel_launch(void* const* d_in, const int* in_sizes, int n_in,
                              void* d_out, int out_size, void* d_ws, size_t ws_size,
                              hipStream_t stream) {
    const float* hr_attn = (const float*)d_in[0];
    const float* hr_hf   = (const float*)d_in[1];
    const float* base_hf = (const float*)d_in[2];
    const float* Wq = (const float*)d_in[3];
    const float* bq = (const float*)d_in[4];
    const float* Wk = (const float*)d_in[5];
    const float* bk = (const float*)d_in[6];
    const float* W1 = (const float*)d_in[7];
    const float* b1 = (const float*)d_in[8];
    const float* W2 = (const float*)d_in[9];
    const float* b2 = (const float*)d_in[10];
    float* out = (float*)d_out;

    float* ws = (float*)d_ws;
    float* hft   = ws;                          // 2*4096*1024 = 8388608
    float* poolK = hft + 8388608;               // 2*256*4096  = 2097152
    float* poolQ = poolK + 2097152;
    float* kemb  = poolQ + 2097152;             // 2*4096*128  = 1048576
    float* qemb  = kemb + 1048576;
    float* kBw   = qemb + 1048576;              // 2*4096*64   = 524288
    float* qAw   = kBw + 524288;
    float* Amat  = qAw + 524288;                // 8192
    float* Bmat  = Amat + 8192;                 // 8192
    float* priw  = Bmat + 8192;                 // 2*4096*16   = 131072
    int*   idxw  = (int*)(priw + 131072);       // 131072
    float* wsm   = (float*)(idxw + 131072);     // 131072

    k_prep<<<32, 256, 0, stream>>>(W1, Amat, Bmat);
    k_pool_t<true><<<dim3(64, 16, NB), 256, 0, stream>>>(hr_hf, poolK, hft);
    k_pool_t<false><<<dim3(64, 16, NB), 256, 0, stream>>>(base_hf, poolQ, nullptr);
    k_encode<<<dim3(64, NB), 256, 0, stream>>>(poolK, Wk, bk, kemb);
    k_encode<<<dim3(64, NB), 256, 0, stream>>>(poolQ, Wq, bq, qemb);
    k_small<<<128, 256, 0, stream>>>(kemb, Bmat, nullptr, kBw);
    k_small<<<128, 256, 0, stream>>>(qemb, Amat, b1, qAw);
    k_topk<<<NB * NN, 256, 0, stream>>>(hr_attn, priw, idxw);
    k_mlpw<<<2048, 256, 0, stream>>>(priw, idxw, qemb, kemb, qAw, kBw, W1, W2, b2, wsm);
    k_gather<<<1024, 256, 0, stream>>>(wsm, idxw, hft, out);
}

// Round 6
// 1142.616 us; speedup vs baseline: 2.6380x; 1.0912x over previous
//
#include <hip/hip_runtime.h>
#include <hip/hip_bf16.h>

#define NB 2
#define NN 4096
#define ND 1024
#define NE 128
#define NHID 64
#define NK 16

// ---------------- pool (and optional transpose) ----------------
// X: (B, 1024, 4096).  pool: (B, 256, 4096).  hft: (B, 4096, 1024)
template<bool DO_T>
__global__ void k_pool_t(const float* __restrict__ X, float* __restrict__ pool, float* __restrict__ hft) {
    int nt = blockIdx.x;          // 0..63 n-tile
    int c  = blockIdx.y;          // 0..15 channel
    int b  = blockIdx.z;
    int t  = threadIdx.x;
    int nn_base = t & 63;
    int g = t >> 6;               // 0..3
    int n0 = nt * 64;
    const float* Xb = X + ((size_t)b * ND + c * 64) * NN + n0;
    __shared__ __align__(16) float xs[64 * 65];

#pragma unroll
    for (int pp = 0; pp < 4; ++pp) {
        int pi16 = pp * 4 + g;
        float s = 0.f;
#pragma unroll
        for (int j = 0; j < 4; ++j) {
            int p = ((pi16 >> 2) << 1) + (j >> 1);
            int q = ((pi16 & 3) << 1) + (j & 1);
            int dl = p * 8 + q;
            float v = Xb[(size_t)dl * NN + nn_base];
            if (DO_T) xs[dl * 65 + nn_base] = v;
            s += v;
        }
        pool[((size_t)b * 256 + c * 16 + pi16) * NN + n0 + nn_base] = s * 0.25f;
    }
    if (DO_T) {
        __syncthreads();
        int dd = t & 63;
#pragma unroll
        for (int i = 0; i < 16; ++i) {
            int nn = i * 4 + g;
            hft[((size_t)b * NN + n0 + nn) * ND + c * 64 + dd] = xs[dd * 65 + nn];
        }
    }
}

// ---------------- encode GEMM: pooled^T (64n x 256) @ W (256x128) + b ----------------
__global__ void k_encode(const float* __restrict__ pool, const float* __restrict__ W,
                         const float* __restrict__ bias, float* __restrict__ emb) {
    int nt = blockIdx.x; int b = blockIdx.y;
    int t = threadIdx.x;
    int n0 = nt * 64;
    int nl = (t & 15) * 4, e0 = (t >> 4) * 8;
    __shared__ __align__(16) float xs[32 * 64];
    __shared__ __align__(16) float wc[32 * 128];
    float acc[4][8] = {};

    for (int d0 = 0; d0 < 256; d0 += 32) {
        __syncthreads();
#pragma unroll
        for (int i = 0; i < 8; ++i) {
            int l = i * 256 + t; int dd = l >> 6, nn = l & 63;
            xs[l] = pool[((size_t)b * 256 + d0 + dd) * NN + n0 + nn];
        }
#pragma unroll
        for (int i = 0; i < 16; ++i) {
            int l = i * 256 + t; int dd = l >> 7, e = l & 127;
            wc[l] = W[(d0 + dd) * NE + e];
        }
        __syncthreads();
#pragma unroll
        for (int dd = 0; dd < 32; ++dd) {
            float4 x = *(float4*)&xs[dd * 64 + nl];
            float w[8];
            *(float4*)&w[0] = *(float4*)&wc[dd * NE + e0];
            *(float4*)&w[4] = *(float4*)&wc[dd * NE + e0 + 4];
            float xv[4] = {x.x, x.y, x.z, x.w};
#pragma unroll
            for (int i = 0; i < 4; ++i)
#pragma unroll
                for (int j = 0; j < 8; ++j) acc[i][j] += xv[i] * w[j];
        }
    }
#pragma unroll
    for (int i = 0; i < 4; ++i) {
        float o[8];
#pragma unroll
        for (int j = 0; j < 8; ++j) o[j] = acc[i][j] + bias[e0 + j];
        *(float4*)&emb[((size_t)b * NN + n0 + nl + i) * NE + e0]     = *(float4*)&o[0];
        *(float4*)&emb[((size_t)b * NN + n0 + nl + i) * NE + e0 + 4] = *(float4*)&o[4];
    }
}

// ---------------- fused small GEMMs: qA = qemb@(W1a+W1c)+b1 ; kB = kemb@(W1b-W1c) ----------------
// grid 256: blocks 0..127 -> q half, 128..255 -> k half. 64 rows per block.
__global__ void k_small2(const float* __restrict__ qemb, const float* __restrict__ kemb,
                         const float* __restrict__ W1, const float* __restrict__ b1,
                         float* __restrict__ qAw, float* __restrict__ kBw) {
    int id = blockIdx.x;
    bool isQ = id < 128;
    int m0 = (id & 127) * 64;
    const float* Xrm = isQ ? qemb : kemb;
    float* outp = isQ ? qAw : kBw;
    int t = threadIdx.x;
    int nl = (t & 15) * 4, e0 = (t >> 4) * 4;
    __shared__ __align__(16) float xs[128 * 68];
    __shared__ __align__(16) float wc[128 * 64];
#pragma unroll
    for (int i = 0; i < 32; ++i) {
        int l = i * 256 + t; int nn = l >> 7, kk = l & 127;
        xs[kk * 68 + nn] = Xrm[(size_t)(m0 + nn) * NE + kk];
    }
#pragma unroll
    for (int i = 0; i < 32; ++i) {
        int l = i * 256 + t;
        float w1c = W1[256 * 64 + l];
        wc[l] = isQ ? (W1[l] + w1c) : (W1[128 * 64 + l] - w1c);
    }
    __syncthreads();
    float acc[4][4] = {};
#pragma unroll
    for (int kk = 0; kk < 128; ++kk) {
        float4 x = *(float4*)&xs[kk * 68 + nl];
        float4 w = *(float4*)&wc[kk * 64 + e0];
        float xv[4] = {x.x, x.y, x.z, x.w};
        float wv[4] = {w.x, w.y, w.z, w.w};
#pragma unroll
        for (int i = 0; i < 4; ++i)
#pragma unroll
            for (int j = 0; j < 4; ++j) acc[i][j] += xv[i] * wv[j];
    }
    float bv[4] = {0.f, 0.f, 0.f, 0.f};
    if (isQ) { bv[0] = b1[e0]; bv[1] = b1[e0 + 1]; bv[2] = b1[e0 + 2]; bv[3] = b1[e0 + 3]; }
#pragma unroll
    for (int i = 0; i < 4; ++i) {
        float4 o = {acc[i][0] + bv[0], acc[i][1] + bv[1], acc[i][2] + bv[2], acc[i][3] + bv[3]};
        *(float4*)&outp[(size_t)(m0 + nl + i) * 64 + e0] = o;
    }
}

// ---------------- top-k (k=16) per row of 4096 ----------------
// Tie-break: JAX top_k prefers the LOWER index on equal values. Pack the
// low 32 bits as (NN-1-idx) so the packed-u64 max picks the lower index.
__device__ __forceinline__ unsigned enc_f(unsigned u) {
    return u ^ ((unsigned)((int)u >> 31) | 0x80000000u);
}
__device__ __forceinline__ float dec_f(unsigned m) {
    unsigned u = (m & 0x80000000u) ? (m ^ 0x80000000u) : ~m;
    return __uint_as_float(u);
}

__global__ void k_topk(const float* __restrict__ attn, float* __restrict__ prior, int* __restrict__ idxo) {
    int row = blockIdx.x;   // b*4096+n
    const float* a = attn + (size_t)row * NN;
    int t = threadIdx.x;
    int lane = t & 63, wv = t >> 6;
    unsigned long long pk[16];
#pragma unroll
    for (int i = 0; i < 16; ++i) {
        int pos = i * 256 + t;
        unsigned ub = enc_f(__float_as_uint(a[pos]));
        pk[i] = ((unsigned long long)ub << 32) | (unsigned)(NN - 1 - pos);
    }
    __shared__ unsigned long long red[4];
    __shared__ unsigned long long win;
    for (int r = 0; r < NK; ++r) {
        unsigned long long m = pk[0];
#pragma unroll
        for (int i = 1; i < 16; ++i) m = (pk[i] > m) ? pk[i] : m;
#pragma unroll
        for (int off = 32; off > 0; off >>= 1) {
            unsigned long long o = __shfl_xor(m, off, 64);
            m = (o > m) ? o : m;
        }
        if (lane == 0) red[wv] = m;
        __syncthreads();
        if (t == 0) {
            unsigned long long w01 = (red[0] > red[1]) ? red[0] : red[1];
            unsigned long long w23 = (red[2] > red[3]) ? red[2] : red[3];
            unsigned long long w0 = (w01 > w23) ? w01 : w23;
            win = w0;
            prior[(size_t)row * NK + r] = dec_f((unsigned)(w0 >> 32));
            idxo[(size_t)row * NK + r] = NN - 1 - (int)(w0 & 0xFFFFFFFFull);
        }
        __syncthreads();
        unsigned long long w0 = win;
#pragma unroll
        for (int i = 0; i < 16; ++i) if (pk[i] == w0) pk[i] = 0ull;
    }
}

// ---------------- MLP rescore + softmax -> weights (B,N,16) ----------------
// Block = 4 rows; wave wv owns row r0+wv, lane = hidden unit e.
__global__ void k_mlpw(const float* __restrict__ prior, const int* __restrict__ idxs,
                       const float* __restrict__ qemb, const float* __restrict__ kemb,
                       const float* __restrict__ qA, const float* __restrict__ kB,
                       const float* __restrict__ W1, const float* __restrict__ W2,
                       const float* __restrict__ b2, float* __restrict__ wout) {
    int bid = blockIdx.x;          // 0..2047
    int t = threadIdx.x;
    int lane = t & 63, wv = t >> 6;
    int r0 = bid * 4;
    __shared__ __align__(16) float w1d[128 * 64];   // 32 KB, block-shared
    __shared__ __align__(16) float qk[64 * 128];    // 32 KB, slot = (row&3)*16+k
    __shared__ float ps[64];
    __shared__ int   js[64];

#pragma unroll
    for (int i = 0; i < 32; ++i) w1d[i * 256 + t] = W1[384 * 64 + i * 256 + t];
    if (t < 64) {
        int r = r0 + (t >> 4);
        ps[t] = prior[(size_t)r * NK + (t & 15)];
        js[t] = idxs[(size_t)r * NK + (t & 15)];
    }
    __syncthreads();

    {   // stage qk products: 4 threads per slot, 32 c's each
        int s = t >> 2, qc = t & 3;
        int r = r0 + (s >> 4);
        int b = r >> 12;
        int j = js[s];
        const float* qrow = qemb + (size_t)r * NE + qc * 32;
        const float* krow = kemb + ((size_t)(b << 12) + j) * NE + qc * 32;
        float* dst = qk + s * NE + qc * 32;
#pragma unroll
        for (int c = 0; c < 32; c += 4) {
            float4 qv = *(const float4*)&qrow[c];
            float4 kv = *(const float4*)&krow[c];
            dst[c]     = qv.x * kv.x;
            dst[c + 1] = qv.y * kv.y;
            dst[c + 2] = qv.z * kv.z;
            dst[c + 3] = qv.w * kv.w;
        }
    }
    __syncthreads();

    int r = r0 + wv;
    int b = r >> 12;
    float qa  = qA[(size_t)r * 64 + lane];
    float wl  = W1[512 * 64 + lane];
    float w2e = W2[lane];
    float bb2 = b2[0];
    float lgk[16];
#pragma unroll
    for (int k = 0; k < 16; ++k) {
        const float* qkr = qk + (wv * 16 + k) * NE;
        float acc = 0.f;
#pragma unroll
        for (int c = 0; c < 128; ++c) acc += qkr[c] * w1d[c * 64 + lane];
        int j = js[wv * 16 + k];
        float h = acc + qa + kB[((size_t)(b << 12) + j) * 64 + lane] + ps[wv * 16 + k] * wl;
        float th = tanhf(0.7978845608028654f * (h + 0.044715f * h * h * h));
        float g = 0.5f * h * (1.f + th);
        float rs = g * w2e;
#pragma unroll
        for (int off = 32; off > 0; off >>= 1) rs += __shfl_xor(rs, off, 64);
        lgk[k] = logf(fmaxf(ps[wv * 16 + k], 1e-8f)) + rs + bb2;
    }
    // softmax over 16, redundantly per lane (cheap), lanes 0..15 write
    float mx = lgk[0];
#pragma unroll
    for (int k = 1; k < 16; ++k) mx = fmaxf(mx, lgk[k]);
    float sum = 0.f;
    float wkk[16];
#pragma unroll
    for (int k = 0; k < 16; ++k) { wkk[k] = expf(lgk[k] - mx); sum += wkk[k]; }
    float inv = 1.f / sum;
    if (lane < 16) wout[(size_t)r * NK + lane] = wkk[lane] * inv;
}

// ---------------- weighted gather, d-tiled for per-XCD L2 residency ----------------
__global__ void k_gather(const float* __restrict__ wsm, const int* __restrict__ idxs,
                         const float* __restrict__ hft, float* __restrict__ out) {
    int id = blockIdx.x;            // 0..1023
    int dt = id & 7;
    int rest = id >> 3;
    int b = rest >> 6;
    int nc = rest & 63;             // 64-row chunk
    int t = threadIdx.x;
    __shared__ float ws[64 * 16];
    __shared__ int   is[64 * 16];
#pragma unroll
    for (int i = 0; i < 4; ++i) {
        int l = i * 256 + t;        // slot = row*16+k
        size_t r = (size_t)(b << 12) + nc * 64 + (l >> 4);
        ws[l] = wsm[r * NK + (l & 15)];
        is[l] = idxs[r * NK + (l & 15)];
    }
    __syncthreads();
    int rg = t >> 5;                // 0..7
    int l32 = t & 31;
    const float* hb = hft + ((size_t)(b << 12)) * ND + dt * 128 + l32 * 4;
    for (int rr = rg; rr < 64; rr += 8) {
        float4 o = {0.f, 0.f, 0.f, 0.f};
#pragma unroll
        for (int k = 0; k < 16; ++k) {
            float w = ws[rr * 16 + k];
            const float4 v = *(const float4*)&hb[(size_t)is[rr * 16 + k] * ND];
            o.x += w * v.x; o.y += w * v.y; o.z += w * v.z; o.w += w * v.w;
        }
        int n = nc * 64 + rr;
        *(float4*)&out[((size_t)(b << 12) + n) * ND + dt * 128 + l32 * 4] = o;
    }
}

// ---------------- launcher ----------------
extern "C" void kernel_launch(void* const* d_in, const int* in_sizes, int n_in,
                              void* d_out, int out_size, void* d_ws, size_t ws_size,
                              hipStream_t stream) {
    const float* hr_attn = (const float*)d_in[0];
    const float* hr_hf   = (const float*)d_in[1];
    const float* base_hf = (const float*)d_in[2];
    const float* Wq = (const float*)d_in[3];
    const float* bq = (const float*)d_in[4];
    const float* Wk = (const float*)d_in[5];
    const float* bk = (const float*)d_in[6];
    const float* W1 = (const float*)d_in[7];
    const float* b1 = (const float*)d_in[8];
    const float* W2 = (const float*)d_in[9];
    const float* b2 = (const float*)d_in[10];
    float* out = (float*)d_out;

    float* ws = (float*)d_ws;
    float* hft   = ws;                          // 2*4096*1024 = 8388608
    float* poolK = hft + 8388608;               // 2*256*4096  = 2097152
    float* poolQ = poolK + 2097152;
    float* kemb  = poolQ + 2097152;             // 2*4096*128  = 1048576
    float* qemb  = kemb + 1048576;
    float* kBw   = qemb + 1048576;              // 2*4096*64   = 524288
    float* qAw   = kBw + 524288;
    float* priw  = qAw + 524288;                // 2*4096*16   = 131072
    int*   idxw  = (int*)(priw + 131072);       // 131072
    float* wsm   = (float*)(idxw + 131072);     // 131072

    k_pool_t<true><<<dim3(64, 16, NB), 256, 0, stream>>>(hr_hf, poolK, hft);
    k_pool_t<false><<<dim3(64, 16, NB), 256, 0, stream>>>(base_hf, poolQ, nullptr);
    k_encode<<<dim3(64, NB), 256, 0, stream>>>(poolK, Wk, bk, kemb);
    k_encode<<<dim3(64, NB), 256, 0, stream>>>(poolQ, Wq, bq, qemb);
    k_small2<<<256, 256, 0, stream>>>(qemb, kemb, W1, b1, qAw, kBw);
    k_topk<<<NB * NN, 256, 0, stream>>>(hr_attn, priw, idxw);
    k_mlpw<<<2048, 256, 0, stream>>>(priw, idxw, qemb, kemb, qAw, kBw, W1, W2, b2, wsm);
    k_gather<<<1024, 256, 0, stream>>>(wsm, idxw, hft, out);
}

// Round 7
// 930.017 us; speedup vs baseline: 3.2410x; 1.2286x over previous
//
#include <hip/hip_runtime.h>
#include <hip/hip_bf16.h>

#define NB 2
#define NN 4096
#define ND 1024
#define NE 128
#define NHID 64
#define NK 16

// ---------------- pool (and optional transpose) ----------------
// X: (B, 1024, 4096).  pool: (B, 256, 4096).  hft: (B, 4096, 1024)
template<bool DO_T>
__global__ void k_pool_t(const float* __restrict__ X, float* __restrict__ pool, float* __restrict__ hft) {
    int nt = blockIdx.x;          // 0..63 n-tile
    int c  = blockIdx.y;          // 0..15 channel
    int b  = blockIdx.z;
    int t  = threadIdx.x;
    int nn_base = t & 63;
    int g = t >> 6;               // 0..3
    int n0 = nt * 64;
    const float* Xb = X + ((size_t)b * ND + c * 64) * NN + n0;
    __shared__ __align__(16) float xs[64 * 65];

#pragma unroll
    for (int pp = 0; pp < 4; ++pp) {
        int pi16 = pp * 4 + g;
        float s = 0.f;
#pragma unroll
        for (int j = 0; j < 4; ++j) {
            int p = ((pi16 >> 2) << 1) + (j >> 1);
            int q = ((pi16 & 3) << 1) + (j & 1);
            int dl = p * 8 + q;
            float v = Xb[(size_t)dl * NN + nn_base];
            if (DO_T) xs[dl * 65 + nn_base] = v;
            s += v;
        }
        pool[((size_t)b * 256 + c * 16 + pi16) * NN + n0 + nn_base] = s * 0.25f;
    }
    if (DO_T) {
        __syncthreads();
        int dd = t & 63;
#pragma unroll
        for (int i = 0; i < 16; ++i) {
            int nn = i * 4 + g;
            hft[((size_t)b * NN + n0 + nn) * ND + c * 64 + dd] = xs[dd * 65 + nn];
        }
    }
}

// ---------------- encode GEMM: pooled^T (64n x 256) @ W (256x128) + b ----------------
__global__ void k_encode(const float* __restrict__ pool, const float* __restrict__ W,
                         const float* __restrict__ bias, float* __restrict__ emb) {
    int nt = blockIdx.x; int b = blockIdx.y;
    int t = threadIdx.x;
    int n0 = nt * 64;
    int nl = (t & 15) * 4, e0 = (t >> 4) * 8;
    __shared__ __align__(16) float xs[32 * 64];
    __shared__ __align__(16) float wc[32 * 128];
    float acc[4][8] = {};

    for (int d0 = 0; d0 < 256; d0 += 32) {
        __syncthreads();
#pragma unroll
        for (int i = 0; i < 8; ++i) {
            int l = i * 256 + t; int dd = l >> 6, nn = l & 63;
            xs[l] = pool[((size_t)b * 256 + d0 + dd) * NN + n0 + nn];
        }
#pragma unroll
        for (int i = 0; i < 16; ++i) {
            int l = i * 256 + t; int dd = l >> 7, e = l & 127;
            wc[l] = W[(d0 + dd) * NE + e];
        }
        __syncthreads();
#pragma unroll
        for (int dd = 0; dd < 32; ++dd) {
            float4 x = *(float4*)&xs[dd * 64 + nl];
            float w[8];
            *(float4*)&w[0] = *(float4*)&wc[dd * NE + e0];
            *(float4*)&w[4] = *(float4*)&wc[dd * NE + e0 + 4];
            float xv[4] = {x.x, x.y, x.z, x.w};
#pragma unroll
            for (int i = 0; i < 4; ++i)
#pragma unroll
                for (int j = 0; j < 8; ++j) acc[i][j] += xv[i] * w[j];
        }
    }
#pragma unroll
    for (int i = 0; i < 4; ++i) {
        float o[8];
#pragma unroll
        for (int j = 0; j < 8; ++j) o[j] = acc[i][j] + bias[e0 + j];
        *(float4*)&emb[((size_t)b * NN + n0 + nl + i) * NE + e0]     = *(float4*)&o[0];
        *(float4*)&emb[((size_t)b * NN + n0 + nl + i) * NE + e0 + 4] = *(float4*)&o[4];
    }
}

// ---------------- fused small GEMMs v2: 32 rows/block, grid 512 ----------------
// qA = qemb@(W1a+W1c)+b1 ; kB = kemb@(W1b-W1c)
__global__ void k_small2(const float* __restrict__ qemb, const float* __restrict__ kemb,
                         const float* __restrict__ W1, const float* __restrict__ b1,
                         float* __restrict__ qAw, float* __restrict__ kBw) {
    int id = blockIdx.x;
    bool isQ = id < 256;
    int m0 = (id & 255) * 32;
    const float* Xrm = isQ ? qemb : kemb;
    float* outp = isQ ? qAw : kBw;
    int t = threadIdx.x;
    int nl = (t & 7) * 4;          // row group 0..28
    int e0 = (t >> 3) * 2;         // col pair 0..62
    __shared__ __align__(16) float xs[128 * 36];   // [kk][nn], pad 36
    __shared__ __align__(16) float wc[128 * 64];
#pragma unroll
    for (int i = 0; i < 16; ++i) {
        int l = i * 256 + t; int nn = l >> 7, kk = l & 127;
        xs[kk * 36 + nn] = Xrm[(size_t)(m0 + nn) * NE + kk];
    }
#pragma unroll
    for (int i = 0; i < 32; ++i) {
        int l = i * 256 + t;
        float w1c = W1[256 * 64 + l];
        wc[l] = isQ ? (W1[l] + w1c) : (W1[128 * 64 + l] - w1c);
    }
    __syncthreads();
    float acc[4][2] = {};
#pragma unroll
    for (int kk = 0; kk < 128; ++kk) {
        float4 x = *(float4*)&xs[kk * 36 + nl];
        float w0 = wc[kk * 64 + e0];
        float w1 = wc[kk * 64 + e0 + 1];
        float xv[4] = {x.x, x.y, x.z, x.w};
#pragma unroll
        for (int i = 0; i < 4; ++i) {
            acc[i][0] += xv[i] * w0;
            acc[i][1] += xv[i] * w1;
        }
    }
    float bv0 = 0.f, bv1 = 0.f;
    if (isQ) { bv0 = b1[e0]; bv1 = b1[e0 + 1]; }
#pragma unroll
    for (int i = 0; i < 4; ++i) {
        float2 o = {acc[i][0] + bv0, acc[i][1] + bv1};
        *(float2*)&outp[(size_t)(m0 + nl + i) * 64 + e0] = o;
    }
}

// ---------------- top-k (k=16) per row of 4096 ----------------
// Tie-break: JAX top_k prefers the LOWER index on equal values. Pack the
// low 32 bits as (NN-1-idx) so the packed-u64 max picks the lower index.
__device__ __forceinline__ unsigned enc_f(unsigned u) {
    return u ^ ((unsigned)((int)u >> 31) | 0x80000000u);
}
__device__ __forceinline__ float dec_f(unsigned m) {
    unsigned u = (m & 0x80000000u) ? (m ^ 0x80000000u) : ~m;
    return __uint_as_float(u);
}

__global__ void k_topk(const float* __restrict__ attn, float* __restrict__ prior, int* __restrict__ idxo) {
    int row = blockIdx.x;   // b*4096+n
    const float* a = attn + (size_t)row * NN;
    int t = threadIdx.x;
    int lane = t & 63, wv = t >> 6;
    unsigned long long pk[16];
#pragma unroll
    for (int i = 0; i < 16; ++i) {
        int pos = i * 256 + t;
        unsigned ub = enc_f(__float_as_uint(a[pos]));
        pk[i] = ((unsigned long long)ub << 32) | (unsigned)(NN - 1 - pos);
    }
    __shared__ unsigned long long red[4];
    __shared__ unsigned long long win;
    for (int r = 0; r < NK; ++r) {
        unsigned long long m = pk[0];
#pragma unroll
        for (int i = 1; i < 16; ++i) m = (pk[i] > m) ? pk[i] : m;
#pragma unroll
        for (int off = 32; off > 0; off >>= 1) {
            unsigned long long o = __shfl_xor(m, off, 64);
            m = (o > m) ? o : m;
        }
        if (lane == 0) red[wv] = m;
        __syncthreads();
        if (t == 0) {
            unsigned long long w01 = (red[0] > red[1]) ? red[0] : red[1];
            unsigned long long w23 = (red[2] > red[3]) ? red[2] : red[3];
            unsigned long long w0 = (w01 > w23) ? w01 : w23;
            win = w0;
            prior[(size_t)row * NK + r] = dec_f((unsigned)(w0 >> 32));
            idxo[(size_t)row * NK + r] = NN - 1 - (int)(w0 & 0xFFFFFFFFull);
        }
        __syncthreads();
        unsigned long long w0 = win;
#pragma unroll
        for (int i = 0; i < 16; ++i) if (pk[i] == w0) pk[i] = 0ull;
    }
}

// ---------------- MLP rescore + softmax -> weights (B,N,16) ----------------
// Block = 4 rows; wave wv owns row r0+wv, lane = hidden unit e.
__global__ void k_mlpw(const float* __restrict__ prior, const int* __restrict__ idxs,
                       const float* __restrict__ qemb, const float* __restrict__ kemb,
                       const float* __restrict__ qA, const float* __restrict__ kB,
                       const float* __restrict__ W1, const float* __restrict__ W2,
                       const float* __restrict__ b2, float* __restrict__ wout) {
    int bid = blockIdx.x;          // 0..2047
    int t = threadIdx.x;
    int lane = t & 63, wv = t >> 6;
    int r0 = bid * 4;
    __shared__ __align__(16) float w1d[128 * 64];   // 32 KB, block-shared
    __shared__ __align__(16) float qk[64 * 128];    // 32 KB, slot = (row&3)*16+k
    __shared__ float ps[64];
    __shared__ int   js[64];

#pragma unroll
    for (int i = 0; i < 32; ++i) w1d[i * 256 + t] = W1[384 * 64 + i * 256 + t];
    if (t < 64) {
        int r = r0 + (t >> 4);
        ps[t] = prior[(size_t)r * NK + (t & 15)];
        js[t] = idxs[(size_t)r * NK + (t & 15)];
    }
    __syncthreads();

    {   // stage qk products: 4 threads per slot, 32 c's each
        int s = t >> 2, qc = t & 3;
        int r = r0 + (s >> 4);
        int b = r >> 12;
        int j = js[s];
        const float* qrow = qemb + (size_t)r * NE + qc * 32;
        const float* krow = kemb + ((size_t)(b << 12) + j) * NE + qc * 32;
        float* dst = qk + s * NE + qc * 32;
#pragma unroll
        for (int c = 0; c < 32; c += 4) {
            float4 qv = *(const float4*)&qrow[c];
            float4 kv = *(const float4*)&krow[c];
            dst[c]     = qv.x * kv.x;
            dst[c + 1] = qv.y * kv.y;
            dst[c + 2] = qv.z * kv.z;
            dst[c + 3] = qv.w * kv.w;
        }
    }
    __syncthreads();

    int r = r0 + wv;
    int b = r >> 12;
    float qa  = qA[(size_t)r * 64 + lane];
    float wl  = W1[512 * 64 + lane];
    float w2e = W2[lane];
    float bb2 = b2[0];
    float lgk[16];
#pragma unroll
    for (int k = 0; k < 16; ++k) {
        const float* qkr = qk + (wv * 16 + k) * NE;
        float acc = 0.f;
#pragma unroll
        for (int c = 0; c < 128; ++c) acc += qkr[c] * w1d[c * 64 + lane];
        int j = js[wv * 16 + k];
        float h = acc + qa + kB[((size_t)(b << 12) + j) * 64 + lane] + ps[wv * 16 + k] * wl;
        float th = tanhf(0.7978845608028654f * (h + 0.044715f * h * h * h));
        float g = 0.5f * h * (1.f + th);
        float rs = g * w2e;
#pragma unroll
        for (int off = 32; off > 0; off >>= 1) rs += __shfl_xor(rs, off, 64);
        lgk[k] = logf(fmaxf(ps[wv * 16 + k], 1e-8f)) + rs + bb2;
    }
    // softmax over 16, redundantly per lane (cheap), lanes 0..15 write
    float mx = lgk[0];
#pragma unroll
    for (int k = 1; k < 16; ++k) mx = fmaxf(mx, lgk[k]);
    float sum = 0.f;
    float wkk[16];
#pragma unroll
    for (int k = 0; k < 16; ++k) { wkk[k] = expf(lgk[k] - mx); sum += wkk[k]; }
    float inv = 1.f / sum;
    if (lane < 16) wout[(size_t)r * NK + lane] = wkk[lane] * inv;
}

// ---------------- weighted gather, d-tiled for per-XCD L2 residency ----------------
__global__ void k_gather(const float* __restrict__ wsm, const int* __restrict__ idxs,
                         const float* __restrict__ hft, float* __restrict__ out) {
    int id = blockIdx.x;            // 0..1023
    int dt = id & 7;
    int rest = id >> 3;
    int b = rest >> 6;
    int nc = rest & 63;             // 64-row chunk
    int t = threadIdx.x;
    __shared__ float ws[64 * 16];
    __shared__ int   is[64 * 16];
#pragma unroll
    for (int i = 0; i < 4; ++i) {
        int l = i * 256 + t;        // slot = row*16+k
        size_t r = (size_t)(b << 12) + nc * 64 + (l >> 4);
        ws[l] = wsm[r * NK + (l & 15)];
        is[l] = idxs[r * NK + (l & 15)];
    }
    __syncthreads();
    int rg = t >> 5;                // 0..7
    int l32 = t & 31;
    const float* hb = hft + ((size_t)(b << 12)) * ND + dt * 128 + l32 * 4;
    for (int rr = rg; rr < 64; rr += 8) {
        float4 o = {0.f, 0.f, 0.f, 0.f};
#pragma unroll
        for (int k = 0; k < 16; ++k) {
            float w = ws[rr * 16 + k];
            const float4 v = *(const float4*)&hb[(size_t)is[rr * 16 + k] * ND];
            o.x += w * v.x; o.y += w * v.y; o.z += w * v.z; o.w += w * v.w;
        }
        int n = nc * 64 + rr;
        *(float4*)&out[((size_t)(b << 12) + n) * ND + dt * 128 + l32 * 4] = o;
    }
}

// ---------------- launcher ----------------
extern "C" void kernel_launch(void* const* d_in, const int* in_sizes, int n_in,
                              void* d_out, int out_size, void* d_ws, size_t ws_size,
                              hipStream_t stream) {
    const float* hr_attn = (const float*)d_in[0];
    const float* hr_hf   = (const float*)d_in[1];
    const float* base_hf = (const float*)d_in[2];
    const float* Wq = (const float*)d_in[3];
    const float* bq = (const float*)d_in[4];
    const float* Wk = (const float*)d_in[5];
    const float* bk = (const float*)d_in[6];
    const float* W1 = (const float*)d_in[7];
    const float* b1 = (const float*)d_in[8];
    const float* W2 = (const float*)d_in[9];
    const float* b2 = (const float*)d_in[10];
    float* out = (float*)d_out;

    float* ws = (float*)d_ws;
    float* hft   = ws;                          // 2*4096*1024 = 8388608
    float* poolK = hft + 8388608;               // 2*256*4096  = 2097152
    float* poolQ = poolK + 2097152;
    float* kemb  = poolQ + 2097152;             // 2*4096*128  = 1048576
    float* qemb  = kemb + 1048576;
    float* kBw   = qemb + 1048576;              // 2*4096*64   = 524288
    float* qAw   = kBw + 524288;
    float* priw  = qAw + 524288;                // 2*4096*16   = 131072
    int*   idxw  = (int*)(priw + 131072);       // 131072
    float* wsm   = (float*)(idxw + 131072);     // 131072

    k_topk<<<NB * NN, 256, 0, stream>>>(hr_attn, priw, idxw);
    k_pool_t<true><<<dim3(64, 16, NB), 256, 0, stream>>>(hr_hf, poolK, hft);
    k_pool_t<false><<<dim3(64, 16, NB), 256, 0, stream>>>(base_hf, poolQ, nullptr);
    k_encode<<<dim3(64, NB), 256, 0, stream>>>(poolK, Wk, bk, kemb);
    k_encode<<<dim3(64, NB), 256, 0, stream>>>(poolQ, Wq, bq, qemb);
    k_small2<<<512, 256, 0, stream>>>(qemb, kemb, W1, b1, qAw, kBw);
    k_mlpw<<<2048, 256, 0, stream>>>(priw, idxw, qemb, kemb, qAw, kBw, W1, W2, b2, wsm);
    k_gather<<<1024, 256, 0, stream>>>(wsm, idxw, hft, out);
}

// Round 9
// 553.195 us; speedup vs baseline: 5.4488x; 1.6812x over previous
//
#include <hip/hip_runtime.h>
#include <hip/hip_bf16.h>

#define NB 2
#define NN 4096
#define ND 1024
#define NE 128
#define NHID 64
#define NK 16

// ---------------- prep: A = W1a+W1c, Bm = W1b-W1c ----------------
__global__ void k_prep(const float* __restrict__ W1, float* __restrict__ A, float* __restrict__ Bm) {
    int i = blockIdx.x * 256 + threadIdx.x;   // 0..8191 = c*64+e
    A[i]  = W1[i]           + W1[256 * 64 + i];
    Bm[i] = W1[128 * 64 + i] - W1[256 * 64 + i];
}

// ---------------- pool (and optional transpose) ----------------
// X: (B, 1024, 4096).  pool: (B, 256, 4096).  hft: (B, 4096, 1024)
template<bool DO_T>
__global__ void k_pool_t(const float* __restrict__ X, float* __restrict__ pool, float* __restrict__ hft) {
    int nt = blockIdx.x;          // 0..63 n-tile
    int c  = blockIdx.y;          // 0..15 channel
    int b  = blockIdx.z;
    int t  = threadIdx.x;
    int nn_base = t & 63;
    int g = t >> 6;               // 0..3
    int n0 = nt * 64;
    const float* Xb = X + ((size_t)b * ND + c * 64) * NN + n0;
    __shared__ __align__(16) float xs[64 * 65];

#pragma unroll
    for (int pp = 0; pp < 4; ++pp) {
        int pi16 = pp * 4 + g;
        float s = 0.f;
#pragma unroll
        for (int j = 0; j < 4; ++j) {
            int p = ((pi16 >> 2) << 1) + (j >> 1);
            int q = ((pi16 & 3) << 1) + (j & 1);
            int dl = p * 8 + q;
            float v = Xb[(size_t)dl * NN + nn_base];
            if (DO_T) xs[dl * 65 + nn_base] = v;
            s += v;
        }
        pool[((size_t)b * 256 + c * 16 + pi16) * NN + n0 + nn_base] = s * 0.25f;
    }
    if (DO_T) {
        __syncthreads();
        int dd = t & 63;
#pragma unroll
        for (int i = 0; i < 16; ++i) {
            int nn = i * 4 + g;
            hft[((size_t)b * NN + n0 + nn) * ND + c * 64 + dd] = xs[dd * 65 + nn];
        }
    }
}

// ---------------- encode GEMM v2: e-split, 256 blocks, 16 KB LDS ----------------
// pooled^T (64n x 256) @ W (256x64-half) + b
__global__ void k_encode(const float* __restrict__ pool, const float* __restrict__ W,
                         const float* __restrict__ bias, float* __restrict__ emb) {
    int nt = blockIdx.x; int b = blockIdx.y; int h = blockIdx.z;
    int t = threadIdx.x;
    int n0 = nt * 64;
    int nl = (t & 15) * 4, e0 = (t >> 4) * 4;
    __shared__ __align__(16) float xs[32 * 64];
    __shared__ __align__(16) float wc[32 * 64];
    float acc[4][4] = {};

    for (int d0 = 0; d0 < 256; d0 += 32) {
        __syncthreads();
#pragma unroll
        for (int i = 0; i < 8; ++i) {
            int l = i * 256 + t; int dd = l >> 6, nn = l & 63;
            xs[l] = pool[((size_t)b * 256 + d0 + dd) * NN + n0 + nn];
        }
#pragma unroll
        for (int i = 0; i < 8; ++i) {
            int l = i * 256 + t; int dd = l >> 6, e = l & 63;
            wc[l] = W[(d0 + dd) * NE + h * 64 + e];
        }
        __syncthreads();
#pragma unroll
        for (int dd = 0; dd < 32; ++dd) {
            float4 x = *(float4*)&xs[dd * 64 + nl];
            float4 w = *(float4*)&wc[dd * 64 + e0];
            float xv[4] = {x.x, x.y, x.z, x.w};
            float wv[4] = {w.x, w.y, w.z, w.w};
#pragma unroll
            for (int i = 0; i < 4; ++i)
#pragma unroll
                for (int j = 0; j < 4; ++j) acc[i][j] += xv[i] * wv[j];
        }
    }
#pragma unroll
    for (int i = 0; i < 4; ++i) {
        float o[4];
#pragma unroll
        for (int j = 0; j < 4; ++j) o[j] = acc[i][j] + bias[h * 64 + e0 + j];
        *(float4*)&emb[((size_t)b * NN + n0 + nl + i) * NE + h * 64 + e0] = *(float4*)&o[0];
    }
}

// ---------------- small GEMMs v3: zero-LDS, wave-per-row ----------------
// blocks 0..2047: qA = qemb@A + b1 ; blocks 2048..4095: kB = kemb@Bm
__global__ void k_small3(const float* __restrict__ qemb, const float* __restrict__ kemb,
                         const float* __restrict__ Amat, const float* __restrict__ Bmat,
                         const float* __restrict__ b1,
                         float* __restrict__ qAw, float* __restrict__ kBw) {
    int id = blockIdx.x;
    bool isQ = id < 2048;
    int t = threadIdx.x;
    int wv = t >> 6, lane = t & 63;
    int row = (id & 2047) * 4 + wv;                 // 0..8191
    const float* Xr = (isQ ? qemb : kemb) + (size_t)row * NE;
    const float* Wm = isQ ? Amat : Bmat;
    float2 xl = *(const float2*)&Xr[lane * 2];      // lane holds x[2l], x[2l+1]
    float acc = 0.f;
#pragma unroll
    for (int c = 0; c < 128; ++c) {
        float xc = __shfl((c & 1) ? xl.y : xl.x, c >> 1, 64);
        acc += xc * Wm[c * 64 + lane];
    }
    if (isQ) acc += b1[lane];
    (isQ ? qAw : kBw)[(size_t)row * 64 + lane] = acc;
}

// ---------------- top-k (k=16) per row of 4096 ----------------
// Tie-break: JAX top_k prefers the LOWER index on equal values. Pack the
// low 32 bits as (NN-1-idx) so the packed-u64 max picks the lower index.
__device__ __forceinline__ unsigned enc_f(unsigned u) {
    return u ^ ((unsigned)((int)u >> 31) | 0x80000000u);
}
__device__ __forceinline__ float dec_f(unsigned m) {
    unsigned u = (m & 0x80000000u) ? (m ^ 0x80000000u) : ~m;
    return __uint_as_float(u);
}

__global__ void k_topk(const float* __restrict__ attn, float* __restrict__ prior, int* __restrict__ idxo) {
    int row = blockIdx.x;   // b*4096+n
    const float* a = attn + (size_t)row * NN;
    int t = threadIdx.x;
    int lane = t & 63, wv = t >> 6;
    unsigned long long pk[16];
#pragma unroll
    for (int i = 0; i < 16; ++i) {
        int pos = i * 256 + t;
        unsigned ub = enc_f(__float_as_uint(a[pos]));
        pk[i] = ((unsigned long long)ub << 32) | (unsigned)(NN - 1 - pos);
    }
    __shared__ unsigned long long red[4];
    __shared__ unsigned long long win;
    for (int r = 0; r < NK; ++r) {
        unsigned long long m = pk[0];
#pragma unroll
        for (int i = 1; i < 16; ++i) m = (pk[i] > m) ? pk[i] : m;
#pragma unroll
        for (int off = 32; off > 0; off >>= 1) {
            unsigned long long o = __shfl_xor(m, off, 64);
            m = (o > m) ? o : m;
        }
        if (lane == 0) red[wv] = m;
        __syncthreads();
        if (t == 0) {
            unsigned long long w01 = (red[0] > red[1]) ? red[0] : red[1];
            unsigned long long w23 = (red[2] > red[3]) ? red[2] : red[3];
            unsigned long long w0 = (w01 > w23) ? w01 : w23;
            win = w0;
            prior[(size_t)row * NK + r] = dec_f((unsigned)(w0 >> 32));
            idxo[(size_t)row * NK + r] = NN - 1 - (int)(w0 & 0xFFFFFFFFull);
        }
        __syncthreads();
        unsigned long long w0 = win;
#pragma unroll
        for (int i = 0; i < 16; ++i) if (pk[i] == w0) pk[i] = 0ull;
    }
}

// ---------------- MLP rescore + softmax -> weights (B,N,16) ----------------
// Block = 4 rows; wave wv owns row r0+wv, lane = hidden unit e.
__global__ void k_mlpw(const float* __restrict__ prior, const int* __restrict__ idxs,
                       const float* __restrict__ qemb, const float* __restrict__ kemb,
                       const float* __restrict__ qA, const float* __restrict__ kB,
                       const float* __restrict__ W1, const float* __restrict__ W2,
                       const float* __restrict__ b2, float* __restrict__ wout) {
    int bid = blockIdx.x;          // 0..2047
    int t = threadIdx.x;
    int lane = t & 63, wv = t >> 6;
    int r0 = bid * 4;
    __shared__ __align__(16) float w1d[128 * 64];   // 32 KB, block-shared
    __shared__ __align__(16) float qk[64 * 128];    // 32 KB, slot = (row&3)*16+k
    __shared__ float ps[64];
    __shared__ int   js[64];

#pragma unroll
    for (int i = 0; i < 32; ++i) w1d[i * 256 + t] = W1[384 * 64 + i * 256 + t];
    if (t < 64) {
        int r = r0 + (t >> 4);
        ps[t] = prior[(size_t)r * NK + (t & 15)];
        js[t] = idxs[(size_t)r * NK + (t & 15)];
    }
    __syncthreads();

    {   // stage qk products: 4 threads per slot, 32 c's each
        int s = t >> 2, qc = t & 3;
        int r = r0 + (s >> 4);
        int b = r >> 12;
        int j = js[s];
        const float* qrow = qemb + (size_t)r * NE + qc * 32;
        const float* krow = kemb + ((size_t)(b << 12) + j) * NE + qc * 32;
        float* dst = qk + s * NE + qc * 32;
#pragma unroll
        for (int c = 0; c < 32; c += 4) {
            float4 qv = *(const float4*)&qrow[c];
            float4 kv = *(const float4*)&krow[c];
            dst[c]     = qv.x * kv.x;
            dst[c + 1] = qv.y * kv.y;
            dst[c + 2] = qv.z * kv.z;
            dst[c + 3] = qv.w * kv.w;
        }
    }
    __syncthreads();

    int r = r0 + wv;
    int b = r >> 12;
    float qa  = qA[(size_t)r * 64 + lane];
    float wl  = W1[512 * 64 + lane];
    float w2e = W2[lane];
    float bb2 = b2[0];
    float lgk[16];
#pragma unroll
    for (int k = 0; k < 16; ++k) {
        const float* qkr = qk + (wv * 16 + k) * NE;
        float acc = 0.f;
#pragma unroll
        for (int c = 0; c < 128; ++c) acc += qkr[c] * w1d[c * 64 + lane];
        int j = js[wv * 16 + k];
        float h = acc + qa + kB[((size_t)(b << 12) + j) * 64 + lane] + ps[wv * 16 + k] * wl;
        float th = tanhf(0.7978845608028654f * (h + 0.044715f * h * h * h));
        float g = 0.5f * h * (1.f + th);
        float rs = g * w2e;
#pragma unroll
        for (int off = 32; off > 0; off >>= 1) rs += __shfl_xor(rs, off, 64);
        lgk[k] = logf(fmaxf(ps[wv * 16 + k], 1e-8f)) + rs + bb2;
    }
    // softmax over 16, redundantly per lane (cheap), lanes 0..15 write
    float mx = lgk[0];
#pragma unroll
    for (int k = 1; k < 16; ++k) mx = fmaxf(mx, lgk[k]);
    float sum = 0.f;
    float wkk[16];
#pragma unroll
    for (int k = 0; k < 16; ++k) { wkk[k] = expf(lgk[k] - mx); sum += wkk[k]; }
    float inv = 1.f / sum;
    if (lane < 16) wout[(size_t)r * NK + lane] = wkk[lane] * inv;
}

// ---------------- weighted gather, d-tiled for per-XCD L2 residency ----------------
__global__ void k_gather(const float* __restrict__ wsm, const int* __restrict__ idxs,
                         const float* __restrict__ hft, float* __restrict__ out) {
    int id = blockIdx.x;            // 0..1023
    int dt = id & 7;
    int rest = id >> 3;
    int b = rest >> 6;
    int nc = rest & 63;             // 64-row chunk
    int t = threadIdx.x;
    __shared__ float ws[64 * 16];
    __shared__ int   is[64 * 16];
#pragma unroll
    for (int i = 0; i < 4; ++i) {
        int l = i * 256 + t;        // slot = row*16+k
        size_t r = (size_t)(b << 12) + nc * 64 + (l >> 4);
        ws[l] = wsm[r * NK + (l & 15)];
        is[l] = idxs[r * NK + (l & 15)];
    }
    __syncthreads();
    int rg = t >> 5;                // 0..7
    int l32 = t & 31;
    const float* hb = hft + ((size_t)(b << 12)) * ND + dt * 128 + l32 * 4;
    for (int rr = rg; rr < 64; rr += 8) {
        float4 o = {0.f, 0.f, 0.f, 0.f};
#pragma unroll
        for (int k = 0; k < 16; ++k) {
            float w = ws[rr * 16 + k];
            const float4 v = *(const float4*)&hb[(size_t)is[rr * 16 + k] * ND];
            o.x += w * v.x; o.y += w * v.y; o.z += w * v.z; o.w += w * v.w;
        }
        int n = nc * 64 + rr;
        *(float4*)&out[((size_t)(b << 12) + n) * ND + dt * 128 + l32 * 4] = o;
    }
}

// ---------------- launcher ----------------
extern "C" void kernel_launch(void* const* d_in, const int* in_sizes, int n_in,
                              void* d_out, int out_size, void* d_ws, size_t ws_size,
                              hipStream_t stream) {
    const float* hr_attn = (const float*)d_in[0];
    const float* hr_hf   = (const float*)d_in[1];
    const float* base_hf = (const float*)d_in[2];
    const float* Wq = (const float*)d_in[3];
    const float* bq = (const float*)d_in[4];
    const float* Wk = (const float*)d_in[5];
    const float* bk = (const float*)d_in[6];
    const float* W1 = (const float*)d_in[7];
    const float* b1 = (const float*)d_in[8];
    const float* W2 = (const float*)d_in[9];
    const float* b2 = (const float*)d_in[10];
    float* out = (float*)d_out;

    float* ws = (float*)d_ws;
    float* hft   = ws;                          // 2*4096*1024 = 8388608
    float* poolK = hft + 8388608;               // 2*256*4096  = 2097152
    float* poolQ = poolK + 2097152;
    float* kemb  = poolQ + 2097152;             // 2*4096*128  = 1048576
    float* qemb  = kemb + 1048576;
    float* kBw   = qemb + 1048576;              // 2*4096*64   = 524288
    float* qAw   = kBw + 524288;
    float* priw  = qAw + 524288;                // 2*4096*16   = 131072
    int*   idxw  = (int*)(priw + 131072);       // 131072
    float* wsm   = (float*)(idxw + 131072);     // 131072
    float* Amat  = wsm + 131072;                // 8192
    float* Bmat  = Amat + 8192;                 // 8192

    k_prep<<<32, 256, 0, stream>>>(W1, Amat, Bmat);
    k_topk<<<NB * NN, 256, 0, stream>>>(hr_attn, priw, idxw);
    k_pool_t<true><<<dim3(64, 16, NB), 256, 0, stream>>>(hr_hf, poolK, hft);
    k_pool_t<false><<<dim3(64, 16, NB), 256, 0, stream>>>(base_hf, poolQ, nullptr);
    k_encode<<<dim3(64, NB, 2), 256, 0, stream>>>(poolK, Wk, bk, kemb);
    k_encode<<<dim3(64, NB, 2), 256, 0, stream>>>(poolQ, Wq, bq, qemb);
    k_small3<<<4096, 256, 0, stream>>>(qemb, kemb, Amat, Bmat, b1, qAw, kBw);
    k_mlpw<<<2048, 256, 0, stream>>>(priw, idxw, qemb, kemb, qAw, kBw, W1, W2, b2, wsm);
    k_gather<<<1024, 256, 0, stream>>>(wsm, idxw, hft, out);
}